// Round 1
// baseline (312.896 us; speedup 1.0000x reference)
//
#include <hip/hip_runtime.h>
#include <hip/hip_bf16.h>

#define HID   128
#define PITCH 136   // bf16 elems per W1t row; 272B, 16B-aligned, spreads banks
#define TPB   256

typedef __attribute__((ext_vector_type(8)))  __bf16 bf16x8;
typedef __attribute__((ext_vector_type(16))) float  f32x16;

// --- pre-kernel: W1 [k][n] fp32  ->  w1t [n][PITCH] bf16 (k-contiguous) ---
__global__ void transpose_w1_kernel(const float* __restrict__ W1,
                                    __bf16* __restrict__ w1t) {
  __shared__ float w[HID * HID];  // 64KB
  for (int i = threadIdx.x; i < HID * HID; i += TPB) w[i] = W1[i];
  __syncthreads();
  for (int c = threadIdx.x; c < HID * (HID / 8); c += TPB) {
    int n  = c >> 4;          // 16 chunks of 8 per output row
    int k0 = (c & 15) << 3;
    bf16x8 v;
#pragma unroll
    for (int j = 0; j < 8; ++j) v[j] = (__bf16)w[(k0 + j) * HID + n];
    *reinterpret_cast<bf16x8*>(&w1t[n * PITCH + k0]) = v;
  }
}

__global__ __launch_bounds__(TPB) void vgae_decode_kernel(
    const float* __restrict__ x,
    const float* __restrict__ W1,
    const __bf16* __restrict__ w1t,   // may be null -> slow in-kernel transpose
    const float* __restrict__ b1,
    const float* __restrict__ W2,
    const float* __restrict__ b2,
    const int* __restrict__ eip,
    const int* __restrict__ ein,
    float* __restrict__ out,
    int E, int n_tiles)
{
  __shared__ __bf16 sW[HID * PITCH];   // 34816 B
  __shared__ float  sb1[HID];
  __shared__ float  sw2[HID];

  if (w1t) {  // linear 16B copy, layouts identical
    const uint4* srcp = reinterpret_cast<const uint4*>(w1t);
    uint4*       dstp = reinterpret_cast<uint4*>(sW);
    for (int i = threadIdx.x; i < (HID * PITCH) / 8; i += TPB) dstp[i] = srcp[i];
  } else {    // fallback: strided global reads (L2-cached after first blocks)
    for (int c = threadIdx.x; c < HID * (HID / 8); c += TPB) {
      int n = c >> 4, k0 = (c & 15) << 3;
      bf16x8 v;
#pragma unroll
      for (int j = 0; j < 8; ++j) v[j] = (__bf16)W1[(k0 + j) * HID + n];
      *reinterpret_cast<bf16x8*>(&sW[n * PITCH + k0]) = v;
    }
  }
  if (threadIdx.x < HID) {
    sb1[threadIdx.x] = b1[threadIdx.x];
    sw2[threadIdx.x] = W2[threadIdx.x];
  }
  __syncthreads();

  const int lane = threadIdx.x & 63;
  const int wave = threadIdx.x >> 6;
  const int m    = lane & 31;   // A-row (edge) / B-col (n) / C-col (n)
  const int half = lane >> 5;   // k-half for A/B frags
  const float b2v = b2[0];

  for (int tile = blockIdx.x; tile < n_tiles; tile += gridDim.x) {
    const int e_base = tile * 128 + wave * 32;   // 32 edges per wave
    const int* ei = (e_base < E) ? eip : ein;
    const int  eo = (e_base < E) ? e_base : (e_base - E);
    const int  e  = eo + m;
    const int  src = ei[e];
    const int  dst = ei[E + e];
    const float* xs = x + (size_t)src * HID;
    const float* xd = x + (size_t)dst * HID;

    f32x16 acc[4] = {};   // 4 n-tiles of 32 cols

#pragma unroll
    for (int ks = 0; ks < 8; ++ks) {
      const int k0 = half * 8 + ks * 16;
      float4 s0 = *reinterpret_cast<const float4*>(xs + k0);
      float4 s1 = *reinterpret_cast<const float4*>(xs + k0 + 4);
      float4 d0 = *reinterpret_cast<const float4*>(xd + k0);
      float4 d1 = *reinterpret_cast<const float4*>(xd + k0 + 4);
      bf16x8 a;   // h = relu(x_s * x_d) in A-frag layout
      a[0] = (__bf16)fmaxf(s0.x * d0.x, 0.f);
      a[1] = (__bf16)fmaxf(s0.y * d0.y, 0.f);
      a[2] = (__bf16)fmaxf(s0.z * d0.z, 0.f);
      a[3] = (__bf16)fmaxf(s0.w * d0.w, 0.f);
      a[4] = (__bf16)fmaxf(s1.x * d1.x, 0.f);
      a[5] = (__bf16)fmaxf(s1.y * d1.y, 0.f);
      a[6] = (__bf16)fmaxf(s1.z * d1.z, 0.f);
      a[7] = (__bf16)fmaxf(s1.w * d1.w, 0.f);
#pragma unroll
      for (int nt = 0; nt < 4; ++nt) {
        bf16x8 bfr = *reinterpret_cast<const bf16x8*>(&sW[(nt * 32 + m) * PITCH + k0]);
        acc[nt] = __builtin_amdgcn_mfma_f32_32x32x16_bf16(a, bfr, acc[nt], 0, 0, 0);
      }
    }

    // epilogue: p[r] = sum_n relu(C[row(r)][n] + b1[n]) * W2[n]  (per-lane over its 4 n's)
    float p[16];
#pragma unroll
    for (int r = 0; r < 16; ++r) p[r] = 0.f;
#pragma unroll
    for (int nt = 0; nt < 4; ++nt) {
      const int n = nt * 32 + m;
      const float b1n = sb1[n];
      const float w2n = sw2[n];
#pragma unroll
      for (int r = 0; r < 16; ++r) {
        float t = fmaxf(acc[nt][r] + b1n, 0.f);
        p[r] = fmaf(t, w2n, p[r]);
      }
    }
    // reduce over the 32 n-lanes (bits 0..4 of lane; bit5=half preserved)
#pragma unroll
    for (int off = 1; off < 32; off <<= 1) {
#pragma unroll
      for (int r = 0; r < 16; ++r) p[r] += __shfl_xor(p[r], off, 64);
    }
    // rows: row = (r&3) + 8*(r>>2) + 4*half ; lanes m<4 store 4 contiguous rows each
    if (m < 4) {
      const int g = m;
      float4 o;
      o.x = 1.f / (1.f + __expf(-(p[g * 4 + 0] + b2v)));
      o.y = 1.f / (1.f + __expf(-(p[g * 4 + 1] + b2v)));
      o.z = 1.f / (1.f + __expf(-(p[g * 4 + 2] + b2v)));
      o.w = 1.f / (1.f + __expf(-(p[g * 4 + 3] + b2v)));
      *reinterpret_cast<float4*>(out + tile * 128 + wave * 32 + g * 8 + half * 4) = o;
    }
  }
}

extern "C" void kernel_launch(void* const* d_in, const int* in_sizes, int n_in,
                              void* d_out, int out_size, void* d_ws, size_t ws_size,
                              hipStream_t stream) {
  const float* x  = (const float*)d_in[0];
  const float* W1 = (const float*)d_in[1];
  const float* b1 = (const float*)d_in[2];
  const float* W2 = (const float*)d_in[3];
  const float* b2 = (const float*)d_in[4];
  const int*  eip = (const int*)d_in[5];
  const int*  ein = (const int*)d_in[6];
  float* out = (float*)d_out;
  const int E = in_sizes[5] / 2;
  const int n_tiles = (2 * E) / 128;

  __bf16* w1t = nullptr;
  if (ws_size >= (size_t)(HID * PITCH * sizeof(__bf16))) {
    w1t = (__bf16*)d_ws;
    transpose_w1_kernel<<<1, TPB, 0, stream>>>(W1, w1t);
  }
  vgae_decode_kernel<<<2560, TPB, 0, stream>>>(x, W1, w1t, b1, W2, b2,
                                               eip, ein, out, E, n_tiles);
}

// Round 2
// 234.645 us; speedup vs baseline: 1.3335x; 1.3335x over previous
//
#include <hip/hip_runtime.h>
#include <hip/hip_bf16.h>

#define HID   128
#define PITCH 136   // bf16 elems per W1t row; 272B, 16B-aligned, conflict-free (measured 0)
#define TPB   256

typedef __attribute__((ext_vector_type(8)))  __bf16 bf16x8;
typedef __attribute__((ext_vector_type(16))) float  f32x16;

// --- pre-kernel: block 0 transposes W1 -> w1t [n][PITCH] bf16 (k-contig);
//     all blocks grid-stride cast x fp32 -> xb bf16 ---
__global__ __launch_bounds__(TPB) void prep_kernel(
    const float* __restrict__ W1, __bf16* __restrict__ w1t,
    const float* __restrict__ x, __bf16* __restrict__ xb, int n_x8) {
  if (xb) {
    for (int i = blockIdx.x * TPB + threadIdx.x; i < n_x8; i += gridDim.x * TPB) {
      float4 a = *reinterpret_cast<const float4*>(x + i * 8);
      float4 b = *reinterpret_cast<const float4*>(x + i * 8 + 4);
      bf16x8 v;
      v[0] = (__bf16)a.x; v[1] = (__bf16)a.y; v[2] = (__bf16)a.z; v[3] = (__bf16)a.w;
      v[4] = (__bf16)b.x; v[5] = (__bf16)b.y; v[6] = (__bf16)b.z; v[7] = (__bf16)b.w;
      *reinterpret_cast<bf16x8*>(xb + i * 8) = v;
    }
  }
  if (blockIdx.x == 0 && w1t) {
    __shared__ float w[HID * HID];
    for (int i = threadIdx.x; i < HID * HID; i += TPB) w[i] = W1[i];
    __syncthreads();
    for (int c = threadIdx.x; c < HID * (HID / 8); c += TPB) {
      int n  = c >> 4;
      int k0 = (c & 15) << 3;
      bf16x8 v;
#pragma unroll
      for (int j = 0; j < 8; ++j) v[j] = (__bf16)w[(k0 + j) * HID + n];
      *reinterpret_cast<bf16x8*>(&w1t[n * PITCH + k0]) = v;
    }
  }
}

__global__ __launch_bounds__(TPB) void vgae_decode_kernel(
    const float* __restrict__ x,
    const __bf16* __restrict__ xb,    // bf16 copy of x (may be null)
    const float* __restrict__ W1,
    const __bf16* __restrict__ w1t,   // may be null -> in-kernel transpose
    const float* __restrict__ b1,
    const float* __restrict__ W2,
    const float* __restrict__ b2,
    const int* __restrict__ eip,
    const int* __restrict__ ein,
    float* __restrict__ out,
    int E, int n_tiles)
{
  __shared__ __bf16 sW[HID * PITCH];   // 34816 B
  __shared__ float  sb1[HID];
  __shared__ float  sw2[HID];

  if (w1t) {  // linear 16B copy, layouts identical
    const uint4* srcp = reinterpret_cast<const uint4*>(w1t);
    uint4*       dstp = reinterpret_cast<uint4*>(sW);
    for (int i = threadIdx.x; i < (HID * PITCH) / 8; i += TPB) dstp[i] = srcp[i];
  } else {
    for (int c = threadIdx.x; c < HID * (HID / 8); c += TPB) {
      int n = c >> 4, k0 = (c & 15) << 3;
      bf16x8 v;
#pragma unroll
      for (int j = 0; j < 8; ++j) v[j] = (__bf16)W1[(k0 + j) * HID + n];
      *reinterpret_cast<bf16x8*>(&sW[n * PITCH + k0]) = v;
    }
  }
  if (threadIdx.x < HID) {
    sb1[threadIdx.x] = b1[threadIdx.x];
    sw2[threadIdx.x] = W2[threadIdx.x];
  }
  __syncthreads();

  const int lane = threadIdx.x & 63;
  const int wave = threadIdx.x >> 6;
  const int m    = lane & 31;   // A-row (edge) / B-col (n) / C-col (n)
  const int half = lane >> 5;   // k-half for A/B frags
  const float b2v = b2[0];

  // --- prefetched indices for the first tile ---
  int tile = blockIdx.x;
  int nsrc = 0, ndst = 0;
  if (tile < n_tiles) {
    const int e_base = tile * 128 + wave * 32;
    const int* ei = (e_base < E) ? eip : ein;
    const int  eo = (e_base < E) ? e_base : (e_base - E);
    nsrc = ei[eo + m];
    ndst = ei[E + eo + m];
  }

  for (; tile < n_tiles; tile += gridDim.x) {
    const int src = nsrc, dst = ndst;

    // prefetch next tile's indices (hide idx-load latency under compute)
    const int tn = tile + gridDim.x;
    if (tn < n_tiles) {
      const int e_base = tn * 128 + wave * 32;
      const int* ei = (e_base < E) ? eip : ein;
      const int  eo = (e_base < E) ? e_base : (e_base - E);
      nsrc = ei[eo + m];
      ndst = ei[E + eo + m];
    }

    f32x16 acc[4] = {};   // 4 n-tiles of 32 cols

    if (xb) {
      const __bf16* xs = xb + (size_t)src * HID;
      const __bf16* xd = xb + (size_t)dst * HID;
      // issue ALL row loads first: 16 outstanding 16B loads per lane
      bf16x8 S[8], D[8];
#pragma unroll
      for (int ks = 0; ks < 8; ++ks) {
        const int k0 = half * 8 + ks * 16;
        S[ks] = *reinterpret_cast<const bf16x8*>(xs + k0);
        D[ks] = *reinterpret_cast<const bf16x8*>(xd + k0);
      }
#pragma unroll
      for (int ks = 0; ks < 8; ++ks) {
        const int k0 = half * 8 + ks * 16;
        bf16x8 a;
#pragma unroll
        for (int j = 0; j < 8; ++j) {
          float p = (float)S[ks][j] * (float)D[ks][j];
          a[j] = (__bf16)fmaxf(p, 0.f);
        }
#pragma unroll
        for (int nt = 0; nt < 4; ++nt) {
          bf16x8 bfr = *reinterpret_cast<const bf16x8*>(&sW[(nt * 32 + m) * PITCH + k0]);
          acc[nt] = __builtin_amdgcn_mfma_f32_32x32x16_bf16(a, bfr, acc[nt], 0, 0, 0);
        }
      }
    } else {  // fp32 fallback (ws too small)
      const float* xs = x + (size_t)src * HID;
      const float* xd = x + (size_t)dst * HID;
#pragma unroll
      for (int ks = 0; ks < 8; ++ks) {
        const int k0 = half * 8 + ks * 16;
        float4 s0 = *reinterpret_cast<const float4*>(xs + k0);
        float4 s1 = *reinterpret_cast<const float4*>(xs + k0 + 4);
        float4 d0 = *reinterpret_cast<const float4*>(xd + k0);
        float4 d1 = *reinterpret_cast<const float4*>(xd + k0 + 4);
        bf16x8 a;
        a[0] = (__bf16)fmaxf(s0.x * d0.x, 0.f);
        a[1] = (__bf16)fmaxf(s0.y * d0.y, 0.f);
        a[2] = (__bf16)fmaxf(s0.z * d0.z, 0.f);
        a[3] = (__bf16)fmaxf(s0.w * d0.w, 0.f);
        a[4] = (__bf16)fmaxf(s1.x * d1.x, 0.f);
        a[5] = (__bf16)fmaxf(s1.y * d1.y, 0.f);
        a[6] = (__bf16)fmaxf(s1.z * d1.z, 0.f);
        a[7] = (__bf16)fmaxf(s1.w * d1.w, 0.f);
#pragma unroll
        for (int nt = 0; nt < 4; ++nt) {
          bf16x8 bfr = *reinterpret_cast<const bf16x8*>(&sW[(nt * 32 + m) * PITCH + k0]);
          acc[nt] = __builtin_amdgcn_mfma_f32_32x32x16_bf16(a, bfr, acc[nt], 0, 0, 0);
        }
      }
    }

    // epilogue: p[r] = sum_n relu(C[row(r)][n] + b1[n]) * W2[n]
    float p[16];
#pragma unroll
    for (int r = 0; r < 16; ++r) p[r] = 0.f;
#pragma unroll
    for (int nt = 0; nt < 4; ++nt) {
      const int n = nt * 32 + m;
      const float b1n = sb1[n];
      const float w2n = sw2[n];
#pragma unroll
      for (int r = 0; r < 16; ++r) {
        float t = fmaxf(acc[nt][r] + b1n, 0.f);
        p[r] = fmaf(t, w2n, p[r]);
      }
    }
#pragma unroll
    for (int off = 1; off < 32; off <<= 1) {
#pragma unroll
      for (int r = 0; r < 16; ++r) p[r] += __shfl_xor(p[r], off, 64);
    }
    // rows: row = (r&3) + 8*(r>>2) + 4*half ; lanes m<4 store 4 contiguous rows each
    if (m < 4) {
      const int g = m;
      float4 o;
      o.x = 1.f / (1.f + __expf(-(p[g * 4 + 0] + b2v)));
      o.y = 1.f / (1.f + __expf(-(p[g * 4 + 1] + b2v)));
      o.z = 1.f / (1.f + __expf(-(p[g * 4 + 2] + b2v)));
      o.w = 1.f / (1.f + __expf(-(p[g * 4 + 3] + b2v)));
      *reinterpret_cast<float4*>(out + tile * 128 + wave * 32 + g * 8 + half * 4) = o;
    }
  }
}

extern "C" void kernel_launch(void* const* d_in, const int* in_sizes, int n_in,
                              void* d_out, int out_size, void* d_ws, size_t ws_size,
                              hipStream_t stream) {
  const float* x  = (const float*)d_in[0];
  const float* W1 = (const float*)d_in[1];
  const float* b1 = (const float*)d_in[2];
  const float* W2 = (const float*)d_in[3];
  const float* b2 = (const float*)d_in[4];
  const int*  eip = (const int*)d_in[5];
  const int*  ein = (const int*)d_in[6];
  float* out = (float*)d_out;
  const int E = in_sizes[5] / 2;
  const int n_tiles = (2 * E) / 128;
  const int n_nodes = in_sizes[0] / HID;
  const int n_x8 = in_sizes[0] / 8;

  const size_t w1t_bytes = (size_t)HID * PITCH * sizeof(__bf16);
  const size_t xb_off    = 65536;  // aligned region after w1t
  const size_t xb_bytes  = (size_t)n_nodes * HID * sizeof(__bf16);

  __bf16* w1t = nullptr;
  __bf16* xb  = nullptr;
  if (ws_size >= w1t_bytes) w1t = (__bf16*)d_ws;
  if (ws_size >= xb_off + xb_bytes) xb = (__bf16*)((char*)d_ws + xb_off);

  if (w1t || xb) {
    int prep_grid = xb ? ((n_x8 + TPB - 1) / TPB < 6400 ? (n_x8 + TPB - 1) / TPB : 6400) : 1;
    prep_kernel<<<prep_grid, TPB, 0, stream>>>(W1, w1t, x, xb, n_x8);
  }
  vgae_decode_kernel<<<2560, TPB, 0, stream>>>(x, xb, W1, w1t, b1, W2, b2,
                                               eip, ein, out, E, n_tiles);
}

// Round 3
// 224.656 us; speedup vs baseline: 1.3928x; 1.0445x over previous
//
#include <hip/hip_runtime.h>
#include <hip/hip_bf16.h>

#define HID   128
#define PITCH 136   // bf16 elems per W1t row; 272B, 16B-aligned, conflict-free (measured 0)
#define TPB   256

typedef __attribute__((ext_vector_type(8))) __bf16 bf16x8;
typedef __attribute__((ext_vector_type(4))) __bf16 bf16x4;
typedef __attribute__((ext_vector_type(4))) float  f32x4;

// --- pre-kernel: block 0 transposes W1 -> w1t [n][PITCH] bf16 (k-contig);
//     all blocks grid-stride cast x fp32 -> xb bf16 (fully coalesced) ---
__global__ __launch_bounds__(TPB) void prep_kernel(
    const float* __restrict__ W1, __bf16* __restrict__ w1t,
    const float* __restrict__ x, __bf16* __restrict__ xb, int n_x4) {
  if (xb) {
    for (int i = blockIdx.x * TPB + threadIdx.x; i < n_x4; i += gridDim.x * TPB) {
      float4 a = reinterpret_cast<const float4*>(x)[i];
      bf16x4 v;
      v[0] = (__bf16)a.x; v[1] = (__bf16)a.y; v[2] = (__bf16)a.z; v[3] = (__bf16)a.w;
      reinterpret_cast<bf16x4*>(xb)[i] = v;
    }
  }
  if (blockIdx.x == 0 && w1t) {
    __shared__ float w[HID * HID];
    for (int i = threadIdx.x; i < HID * HID; i += TPB) w[i] = W1[i];
    __syncthreads();
    for (int c = threadIdx.x; c < HID * (HID / 8); c += TPB) {
      int n  = c >> 4;
      int k0 = (c & 15) << 3;
      bf16x8 v;
#pragma unroll
      for (int j = 0; j < 8; ++j) v[j] = (__bf16)w[(k0 + j) * HID + n];
      *reinterpret_cast<bf16x8*>(&w1t[n * PITCH + k0]) = v;
    }
  }
}

// 16x16x32 MFMA decode: 16 edges per wave, quad-coalesced row gathers.
__global__ __launch_bounds__(TPB) void vgae_decode_kernel(
    const __bf16* __restrict__ xb,
    const __bf16* __restrict__ w1t,
    const float* __restrict__ b1,
    const float* __restrict__ W2,
    const float* __restrict__ b2,
    const int* __restrict__ eip,
    const int* __restrict__ ein,
    float* __restrict__ out,
    int E, int n_tiles)
{
  __shared__ __bf16 sW[HID * PITCH];   // 34816 B
  __shared__ float  sb1[HID];
  __shared__ float  sw2[HID];

  {  // linear 16B copy from w1t (layouts identical)
    const uint4* srcp = reinterpret_cast<const uint4*>(w1t);
    uint4*       dstp = reinterpret_cast<uint4*>(sW);
    for (int i = threadIdx.x; i < (HID * PITCH) / 8; i += TPB) dstp[i] = srcp[i];
  }
  if (threadIdx.x < HID) {
    sb1[threadIdx.x] = b1[threadIdx.x];
    sw2[threadIdx.x] = W2[threadIdx.x];
  }
  __syncthreads();

  const int lane = threadIdx.x & 63;
  const int wave = threadIdx.x >> 6;
  const int m    = lane & 15;   // edge-within-wave (A row) / n-within-tile (B col, C col)
  const int quad = lane >> 4;   // k-chunk for A/B frags; C row group
  const float b2v = b2[0];

  // prefetch first tile's indices
  int tile = blockIdx.x;
  int nsrc = 0, ndst = 0;
  if (tile < n_tiles) {
    const int e_base = tile * 64 + wave * 16;   // 16 edges per wave
    const int* ei = (e_base < E) ? eip : ein;
    const int  eo = (e_base < E) ? e_base : (e_base - E);
    nsrc = ei[eo + m];
    ndst = ei[E + eo + m];
  }

  for (; tile < n_tiles; tile += gridDim.x) {
    const int src = nsrc, dst = ndst;
    const __bf16* xs = xb + (size_t)src * HID;
    const __bf16* xd = xb + (size_t)dst * HID;

    // issue all 8 row-chunk loads up front. For load kt, lanes {m,m+16,m+32,m+48}
    // cover one contiguous 64B line of row m -> 16 line-transactions/instr (min).
    bf16x8 S[4], D[4];
#pragma unroll
    for (int kt = 0; kt < 4; ++kt) {
      const int k0 = kt * 32 + quad * 8;
      S[kt] = *reinterpret_cast<const bf16x8*>(xs + k0);
      D[kt] = *reinterpret_cast<const bf16x8*>(xd + k0);
    }

    // prefetch next tile's indices under the row loads
    const int tn = tile + gridDim.x;
    if (tn < n_tiles) {
      const int e_base = tn * 64 + wave * 16;
      const int* ei = (e_base < E) ? eip : ein;
      const int  eo = (e_base < E) ? e_base : (e_base - E);
      nsrc = ei[eo + m];
      ndst = ei[E + eo + m];
    }

    f32x4 acc[8] = {};   // 8 n-tiles of 16 cols

#pragma unroll
    for (int kt = 0; kt < 4; ++kt) {
      const int k0 = kt * 32 + quad * 8;
      bf16x8 a;   // h = relu(x_s * x_d), A-frag layout
#pragma unroll
      for (int j = 0; j < 8; ++j) {
        float p = (float)S[kt][j] * (float)D[kt][j];
        a[j] = (__bf16)fmaxf(p, 0.f);
      }
#pragma unroll
      for (int nt = 0; nt < 8; ++nt) {
        bf16x8 bfr = *reinterpret_cast<const bf16x8*>(&sW[(nt * 16 + m) * PITCH + k0]);
        acc[nt] = __builtin_amdgcn_mfma_f32_16x16x32_bf16(a, bfr, acc[nt], 0, 0, 0);
      }
    }

    // epilogue: per lane, 4 edge-rows (quad*4+r), col n = m.
    // p[r] = sum_n relu(C[row][n] + b1[n]) * W2[n]
    float p[4] = {0.f, 0.f, 0.f, 0.f};
#pragma unroll
    for (int nt = 0; nt < 8; ++nt) {
      const int n = nt * 16 + m;
      const float b1n = sb1[n];
      const float w2n = sw2[n];
#pragma unroll
      for (int r = 0; r < 4; ++r) {
        float t = fmaxf(acc[nt][r] + b1n, 0.f);
        p[r] = fmaf(t, w2n, p[r]);
      }
    }
    // reduce over the 16 n-lanes (bits 0..3; quad bits preserved)
#pragma unroll
    for (int off = 1; off < 16; off <<= 1) {
#pragma unroll
      for (int r = 0; r < 4; ++r) p[r] += __shfl_xor(p[r], off, 64);
    }
    // lane m==0 of each quad stores rows quad*4..quad*4+3
    if (m == 0) {
      float4 o;
      o.x = 1.f / (1.f + __expf(-(p[0] + b2v)));
      o.y = 1.f / (1.f + __expf(-(p[1] + b2v)));
      o.z = 1.f / (1.f + __expf(-(p[2] + b2v)));
      o.w = 1.f / (1.f + __expf(-(p[3] + b2v)));
      *reinterpret_cast<float4*>(out + tile * 64 + wave * 16 + quad * 4) = o;
    }
  }
}

// fp32 fallback (ws too small for xb): previous-round structure, 32x32 shape
__global__ __launch_bounds__(TPB) void vgae_decode_fallback(
    const float* __restrict__ x,
    const float* __restrict__ W1,
    const float* __restrict__ b1,
    const float* __restrict__ W2,
    const float* __restrict__ b2,
    const int* __restrict__ eip,
    const int* __restrict__ ein,
    float* __restrict__ out,
    int E, int n_tiles)
{
  __shared__ __bf16 sW[HID * PITCH];
  __shared__ float  sb1[HID];
  __shared__ float  sw2[HID];
  for (int c = threadIdx.x; c < HID * (HID / 8); c += TPB) {
    int n = c >> 4, k0 = (c & 15) << 3;
    bf16x8 v;
#pragma unroll
    for (int j = 0; j < 8; ++j) v[j] = (__bf16)W1[(k0 + j) * HID + n];
    *reinterpret_cast<bf16x8*>(&sW[n * PITCH + k0]) = v;
  }
  if (threadIdx.x < HID) { sb1[threadIdx.x] = b1[threadIdx.x]; sw2[threadIdx.x] = W2[threadIdx.x]; }
  __syncthreads();
  const int lane = threadIdx.x & 63, wave = threadIdx.x >> 6;
  const int m = lane & 15, quad = lane >> 4;
  const float b2v = b2[0];
  for (int tile = blockIdx.x; tile < n_tiles; tile += gridDim.x) {
    const int e_base = tile * 64 + wave * 16;
    const int* ei = (e_base < E) ? eip : ein;
    const int  eo = (e_base < E) ? e_base : (e_base - E);
    const int src = ei[eo + m], dst = ei[E + eo + m];
    const float* xs = x + (size_t)src * HID;
    const float* xd = x + (size_t)dst * HID;
    f32x4 acc[8] = {};
#pragma unroll
    for (int kt = 0; kt < 4; ++kt) {
      const int k0 = kt * 32 + quad * 8;
      float4 s0 = *reinterpret_cast<const float4*>(xs + k0);
      float4 s1 = *reinterpret_cast<const float4*>(xs + k0 + 4);
      float4 d0 = *reinterpret_cast<const float4*>(xd + k0);
      float4 d1 = *reinterpret_cast<const float4*>(xd + k0 + 4);
      bf16x8 a;
      a[0] = (__bf16)fmaxf(s0.x * d0.x, 0.f); a[1] = (__bf16)fmaxf(s0.y * d0.y, 0.f);
      a[2] = (__bf16)fmaxf(s0.z * d0.z, 0.f); a[3] = (__bf16)fmaxf(s0.w * d0.w, 0.f);
      a[4] = (__bf16)fmaxf(s1.x * d1.x, 0.f); a[5] = (__bf16)fmaxf(s1.y * d1.y, 0.f);
      a[6] = (__bf16)fmaxf(s1.z * d1.z, 0.f); a[7] = (__bf16)fmaxf(s1.w * d1.w, 0.f);
#pragma unroll
      for (int nt = 0; nt < 8; ++nt) {
        bf16x8 bfr = *reinterpret_cast<const bf16x8*>(&sW[(nt * 16 + m) * PITCH + k0]);
        acc[nt] = __builtin_amdgcn_mfma_f32_16x16x32_bf16(a, bfr, acc[nt], 0, 0, 0);
      }
    }
    float p[4] = {0.f, 0.f, 0.f, 0.f};
#pragma unroll
    for (int nt = 0; nt < 8; ++nt) {
      const int n = nt * 16 + m;
      const float b1n = sb1[n], w2n = sw2[n];
#pragma unroll
      for (int r = 0; r < 4; ++r) p[r] = fmaf(fmaxf(acc[nt][r] + b1n, 0.f), w2n, p[r]);
    }
#pragma unroll
    for (int off = 1; off < 16; off <<= 1)
#pragma unroll
      for (int r = 0; r < 4; ++r) p[r] += __shfl_xor(p[r], off, 64);
    if (m == 0) {
      float4 o;
      o.x = 1.f / (1.f + __expf(-(p[0] + b2v)));
      o.y = 1.f / (1.f + __expf(-(p[1] + b2v)));
      o.z = 1.f / (1.f + __expf(-(p[2] + b2v)));
      o.w = 1.f / (1.f + __expf(-(p[3] + b2v)));
      *reinterpret_cast<float4*>(out + tile * 64 + wave * 16 + quad * 4) = o;
    }
  }
}

extern "C" void kernel_launch(void* const* d_in, const int* in_sizes, int n_in,
                              void* d_out, int out_size, void* d_ws, size_t ws_size,
                              hipStream_t stream) {
  const float* x  = (const float*)d_in[0];
  const float* W1 = (const float*)d_in[1];
  const float* b1 = (const float*)d_in[2];
  const float* W2 = (const float*)d_in[3];
  const float* b2 = (const float*)d_in[4];
  const int*  eip = (const int*)d_in[5];
  const int*  ein = (const int*)d_in[6];
  float* out = (float*)d_out;
  const int E = in_sizes[5] / 2;
  const int n_tiles = (2 * E) / 64;
  const int n_nodes = in_sizes[0] / HID;
  const int n_x4 = in_sizes[0] / 4;

  const size_t w1t_bytes = (size_t)HID * PITCH * sizeof(__bf16);
  const size_t xb_off    = 65536;
  const size_t xb_bytes  = (size_t)n_nodes * HID * sizeof(__bf16);

  __bf16* w1t = nullptr;
  __bf16* xb  = nullptr;
  if (ws_size >= w1t_bytes) w1t = (__bf16*)d_ws;
  if (ws_size >= xb_off + xb_bytes) xb = (__bf16*)((char*)d_ws + xb_off);

  if (w1t && xb) {
    int prep_grid = (n_x4 + TPB - 1) / TPB;
    if (prep_grid > 6400) prep_grid = 6400;
    prep_kernel<<<prep_grid, TPB, 0, stream>>>(W1, w1t, x, xb, n_x4);
    vgae_decode_kernel<<<2560, TPB, 0, stream>>>(xb, w1t, b1, W2, b2,
                                                 eip, ein, out, E, n_tiles);
  } else {
    vgae_decode_fallback<<<2560, TPB, 0, stream>>>(x, W1, b1, W2, b2,
                                                   eip, ein, out, E, n_tiles);
  }
}